// Round 3
// baseline (3783.559 us; speedup 1.0000x reference)
//
#include <hip/hip_runtime.h>

#define NG 8      // independent batch groups (16 rows each)
#define GB 12u    // blocks per group: 8 layer1 + 4 layer2

// One monotonic barrier counter per group, 128 B apart. Zeroed by init_kernel
// (stream-ordered before the main kernel) every launch.
__device__ unsigned int g_cnt[NG * 32];

typedef __attribute__((ext_vector_type(8))) short short8;
typedef __attribute__((ext_vector_type(4))) float floatx4;

// Split fp32 v into bf16 hi + bf16 lo (residual), packed (hi<<16)|lo.
__device__ __forceinline__ unsigned int split_pack(float v) {
    unsigned int u  = __float_as_uint(v);
    unsigned int hb = u & 0xffff0000u;          // truncated-bf16 hi, exact in fp32
    float r = v - __uint_as_float(hb);          // exact residual
    return hb | (__float_as_uint(r) >> 16);
}

__device__ __forceinline__ float sigmoidf_(float z) {
    return 1.0f / (1.0f + __expf(-z));
}

// ---- device-coherent h data path ----
// Agent-scope relaxed atomics compile to sc1 memory ops: stores write through
// to the coherence point (L3, no dirty L2 lines => arrival wbl2 has nothing to
// flush), loads fetch from L3 (never stale => no per-step acquire/buffer_inv
// needed, so weights/x stay warm in L1/L2 across all 512 steps).
__device__ __forceinline__ void st_coh(unsigned int* p, unsigned int v) {
    __hip_atomic_store(p, v, __ATOMIC_RELAXED, __HIP_MEMORY_SCOPE_AGENT);
}

__device__ __forceinline__ void unpack_coh(const unsigned int* hp, short8& ah, short8& al) {
    unsigned long long q[4];
#pragma unroll
    for (int j = 0; j < 4; ++j)
        q[j] = __hip_atomic_load((const unsigned long long*)(hp) + j,
                                 __ATOMIC_RELAXED, __HIP_MEMORY_SCOPE_AGENT);
#pragma unroll
    for (int j = 0; j < 4; ++j) {
        unsigned int lo = (unsigned int)q[j];
        unsigned int hi = (unsigned int)(q[j] >> 32);
        ah[2 * j]     = (short)(lo >> 16);
        al[2 * j]     = (short)(lo & 0xffffu);
        ah[2 * j + 1] = (short)(hi >> 16);
        al[2 * j + 1] = (short)(hi & 0xffffu);
    }
}

__device__ __forceinline__ void cvt_x(const float* xp, short8& ah, short8& al) {
    float4 xa = *(const float4*)(xp);
    float4 xb = *(const float4*)(xp + 4);
    float xv[8] = {xa.x, xa.y, xa.z, xa.w, xb.x, xb.y, xb.z, xb.w};
#pragma unroll
    for (int j = 0; j < 8; ++j) {
        unsigned int u  = __float_as_uint(xv[j]);
        unsigned int hb = u & 0xffff0000u;
        float r = xv[j] - __uint_as_float(hb);
        ah[j] = (short)(u >> 16);
        al[j] = (short)(__float_as_uint(r) >> 16);
    }
}

// Group-local barrier, round-3 protocol:
//   pre     : __syncthreads -- each wave drains its own vmem (incl. the sc1
//             write-through h stores, which complete at L3) before s_barrier.
//   arrival : RELEASE agent-scope RMW. Its vmcnt-drain + wbl2 orders the
//             counter bump after the h stores; wbl2 is near-free now because
//             the sc1 h stores never dirty L2.
//   spin    : RELAXED agent-scope RMW (fetch_add 0) -- executes memory-side at
//             L3, never stale, no cache maintenance per poll.
//   observe : NO acquire fence. Consumers read h via sc1 loads that always
//             fetch from L3; __syncthreads provides the workgroup-level
//             ordering so those loads cannot be hoisted above the barrier.
//             => L1/L2 are never invalidated: weights and x stay cached.
__device__ __forceinline__ void gbar(unsigned int* cnt, unsigned int target) {
    __syncthreads();
    if (threadIdx.x == 0) {
        __hip_atomic_fetch_add(cnt, 1u, __ATOMIC_RELEASE, __HIP_MEMORY_SCOPE_AGENT);
        while (__hip_atomic_fetch_add(cnt, 0u, __ATOMIC_RELAXED, __HIP_MEMORY_SCOPE_AGENT) < target) {}
    }
    __syncthreads();
}

// One LSTM layer role for one batch group (16 rows). Wave owns the group's
// m-tile x 2 column-tiles (8 units, all 4 gates). Weights pre-split to bf16
// hi/lo MFMA B-fragments in registers.
// MFMA 16x16x32_bf16: A: m=lane&15,k=quad*8+j ; D: col=lane&15, row=quad*4+r
template<int NKC, int KX, int GW, int UU, bool L1>
__device__ void lstm_role(const float* __restrict__ x,
                          const float* __restrict__ Wm, const float* __restrict__ Um,
                          const float* __restrict__ bias,
                          unsigned int* __restrict__ h1pk, unsigned int* __restrict__ h2pk,
                          float* __restrict__ out, unsigned int* __restrict__ cnt,
                          int m0, int wid, float (*zex)[17])
{
    const int lane = threadIdx.x & 63;
    const int n    = lane & 15;
    const int quad = lane >> 4;
    const int gate = n >> 2;
    const int u0   = wid * 8;             // 8 units per wave (2 coltiles x 4)
    const int arow = m0 + n;              // A-fragment row this lane loads
    const int b_l  = lane >> 2;           // epilogue: batch-local 0..15
    const int ul   = lane & 3;            // epilogue: unit-local 0..3

    // ---- one-time: weight B-fragments (hi/lo split), bias ----
    short8 bh[2][NKC], bl[2][NKC];
    float bias_v[2];
#pragma unroll
    for (int c = 0; c < 2; ++c) {
        const int col = gate * UU + u0 + c * 4 + (n & 3);
        bias_v[c] = bias[col];
#pragma unroll
        for (int kc = 0; kc < NKC; ++kc) {
#pragma unroll
            for (int j = 0; j < 8; ++j) {
                int k = kc * 32 + quad * 8 + j;
                float w = (k < KX) ? Wm[k * GW + col] : Um[(k - KX) * GW + col];
                unsigned int p = split_pack(w);
                bh[c][kc][j] = (short)(p >> 16);
                bl[c][kc][j] = (short)(p & 0xffffu);
            }
        }
    }

    // ---- zero the "step -1" h slice this wave owns (ws is poisoned) ----
#pragma unroll
    for (int c = 0; c < 2; ++c) {
        if (L1) st_coh(&h1pk[32768 + (m0 + b_l) * 256 + u0 + c * 4 + ul], 0u);
        else    st_coh(&h2pk[16384 + (m0 + b_l) * 128 + u0 + c * 4 + ul], 0u);
    }
    float cst[2] = {0.f, 0.f};

    // ---- init barrier: publishes the [-1]-slot zeros within the group ----
    gbar(cnt, GB * 1u);

    for (int it = 0; it <= 512; ++it) {
        const bool active = L1 ? (it < 512) : (it >= 1);
        if (active) {
            const int s = L1 ? it : (it - 1);
            floatx4 acc[2];
#pragma unroll
            for (int c = 0; c < 2; ++c)
                acc[c] = {bias_v[c], bias_v[c], bias_v[c], bias_v[c]};

            const float* xsrc = L1 ? (x + (size_t)arow * (512 * 64) + s * 64) : nullptr;
            const unsigned int* hA = L1
                ? (h1pk + ((it + 1) & 1) * 32768 + arow * 256)   // h1[s-1]
                : (h1pk + (s & 1) * 32768 + arow * 256);         // h1[s]
            const unsigned int* hB = L1
                ? nullptr
                : (h2pk + ((s + 1) & 1) * 16384 + arow * 128);   // h2[s-1]

#pragma unroll
            for (int kc = 0; kc < NKC; ++kc) {
                short8 ah, al;
                if (L1) {
                    if (kc < 2) cvt_x(xsrc + kc * 32 + quad * 8, ah, al);
                    else        unpack_coh(hA + (kc - 2) * 32 + quad * 8, ah, al);
                } else {
                    if (kc < 8) unpack_coh(hA + kc * 32 + quad * 8, ah, al);
                    else        unpack_coh(hB + (kc - 8) * 32 + quad * 8, ah, al);
                }
#pragma unroll
                for (int c = 0; c < 2; ++c) {
                    acc[c] = __builtin_amdgcn_mfma_f32_16x16x32_bf16(ah, bh[c][kc], acc[c], 0, 0, 0);
                    acc[c] = __builtin_amdgcn_mfma_f32_16x16x32_bf16(ah, bl[c][kc], acc[c], 0, 0, 0);
                    acc[c] = __builtin_amdgcn_mfma_f32_16x16x32_bf16(al, bh[c][kc], acc[c], 0, 0, 0);
                }
            }

            // ---- epilogue: per coltile, gate-gather via per-wave LDS tile.
            // Wave-level lgkmcnt(0) drains the ds_writes of ALL lanes of this
            // wave before any lane's read; memory clobber stops reordering. ----
#pragma unroll
            for (int c = 0; c < 2; ++c) {
#pragma unroll
                for (int r = 0; r < 4; ++r) zex[quad * 4 + r][n] = acc[c][r];
                asm volatile("s_waitcnt lgkmcnt(0)" ::: "memory");
                float zi = zex[b_l][ 0 + ul];
                float zf = zex[b_l][ 4 + ul];
                float zg = zex[b_l][ 8 + ul];
                float zo = zex[b_l][12 + ul];
                asm volatile("s_waitcnt lgkmcnt(0)" ::: "memory");
                float ig = sigmoidf_(zi);
                float fg = sigmoidf_(zf);
                float gg = fmaxf(zg, 0.f);
                float og = sigmoidf_(zo);
                cst[c] = fg * cst[c] + ig * gg;
                float h = og * fmaxf(cst[c], 0.f);
                unsigned int p = split_pack(h);
                int b = m0 + b_l;
                if (L1) {
                    st_coh(&h1pk[(it & 1) * 32768 + b * 256 + u0 + c * 4 + ul], p);
                } else {
                    st_coh(&h2pk[(s & 1) * 16384 + b * 128 + u0 + c * 4 + ul], p);
                    if (s == 511) out[b * 128 + u0 + c * 4 + ul] = h;
                }
            }
        }
        if (it < 512) gbar(cnt, GB * (unsigned)(it + 2));
    }
}

__global__ void __launch_bounds__(256, 1)
lstm_fused_kernel(const float* __restrict__ x,
                  const float* __restrict__ W1, const float* __restrict__ U1,
                  const float* __restrict__ b1,
                  const float* __restrict__ W2, const float* __restrict__ U2,
                  const float* __restrict__ b2,
                  float* __restrict__ out, unsigned int* __restrict__ ws)
{
    __shared__ float zex[4][16][17];       // per-wave gate-gather tiles
    unsigned int* h1pk = ws;               // [2][128][256] packed hi/lo bf16
    unsigned int* h2pk = ws + 65536;       // [2][128][128]
    const int g    = blockIdx.x & 7;       // batch group
    const int role = blockIdx.x >> 3;      // 0..7 layer1, 8..11 layer2
    const int wv   = threadIdx.x >> 6;
    const int m0   = g * 16;
    unsigned int* cnt = &g_cnt[g * 32];
    if (role < 8) {
        // layer1: 8 blocks x 4 waves = 32 unit-waves x 8 units = 256 units
        lstm_role<10, 64, 1024, 256, true >(x, W1, U1, b1, h1pk, h2pk, out, cnt,
                                            m0, role * 4 + wv, zex[wv]);
    } else {
        // layer2: 4 blocks x 4 waves = 16 unit-waves x 8 units = 128 units
        lstm_role<12, 256, 512, 128, false>(x, W2, U2, b2, h1pk, h2pk, out, cnt,
                                            m0, (role - 8) * 4 + wv, zex[wv]);
    }
}

// Pre-kernel (plain launch, cannot fail): zero barrier counters, write the
// diagnostic sentinel. Stream order publishes both to the main kernel.
// Signatures if main kernel fails: absmax~7 => main never ran (launch issue);
// absmax~0.162 => main ran but produced zeros (coherence issue).
__global__ void init_kernel(float* __restrict__ out) {
    int t = blockIdx.x * 256 + threadIdx.x;
    if (t < NG * 32) g_cnt[t] = 0u;
    if (t < 16384) out[t] = 7.0f;
}

extern "C" void kernel_launch(void* const* d_in, const int* in_sizes, int n_in,
                              void* d_out, int out_size, void* d_ws, size_t ws_size,
                              hipStream_t stream) {
    const float* x  = (const float*)d_in[0];
    const float* W1 = (const float*)d_in[1];
    const float* U1 = (const float*)d_in[2];
    const float* b1 = (const float*)d_in[3];
    const float* W2 = (const float*)d_in[4];
    const float* U2 = (const float*)d_in[5];
    const float* b2 = (const float*)d_in[6];
    float* out = (float*)d_out;
    unsigned int* ws = (unsigned int*)d_ws;
    init_kernel<<<64, 256, 0, stream>>>(out);
    lstm_fused_kernel<<<96, 256, 0, stream>>>(x, W1, U1, b1, W2, U2, b2, out, ws);
}

// Round 4
// 1961.136 us; speedup vs baseline: 1.9293x; 1.9293x over previous
//
#include <hip/hip_runtime.h>

#define NG 8      // independent batch groups (16 rows each)

// Two monotonic counters per group, 128 B apart: [g*64]=cntA (layer1, 8
// arrivals/step), [g*64+32]=cntB (layer2, 4 arrivals/step). Zeroed by
// init_kernel (stream-ordered before the main kernel) every launch.
__device__ unsigned int g_cnt[NG * 64];

typedef __attribute__((ext_vector_type(8))) short short8;
typedef __attribute__((ext_vector_type(4))) float floatx4;

// Split fp32 v into bf16 hi + bf16 lo (residual), packed (hi<<16)|lo.
__device__ __forceinline__ unsigned int split_pack(float v) {
    unsigned int u  = __float_as_uint(v);
    unsigned int hb = u & 0xffff0000u;          // truncated-bf16 hi, exact in fp32
    float r = v - __uint_as_float(hb);          // exact residual
    return hb | (__float_as_uint(r) >> 16);
}

__device__ __forceinline__ float sigmoidf_(float z) {
    return 1.0f / (1.0f + __expf(-z));
}

// ---- device-coherent h data path ----
// sc1 stores write through to the coherence point (no dirty L2 => arrival wbl2
// is ~free). sc1 loads are used ONLY for the once-per-step block-cooperative
// tile staging (r3 lesson: per-lane sc1 gathers = coherence-point latency on
// every fragment, 4x redundant across waves => 2x regression).
__device__ __forceinline__ void st_coh(unsigned int* p, unsigned int v) {
    __hip_atomic_store(p, v, __ATOMIC_RELAXED, __HIP_MEMORY_SCOPE_AGENT);
}
__device__ __forceinline__ unsigned long long ld_coh64(const unsigned long long* p) {
    return __hip_atomic_load(p, __ATOMIC_RELAXED, __HIP_MEMORY_SCOPE_AGENT);
}

// Stage a 16-row tile (RS uints/row, contiguous in global) into XOR-swizzled
// LDS. Swizzle: uint col c of row r stored at c ^ ((r&7)<<2) -- flips bits 2-4
// so the 16 lanes' stride-RS ds_read_b128s spread over all 32 banks (8/bank,
// the b128 floor). All NJ loads issued before writes to overlap latency.
template<int RS, int NJ>
__device__ __forceinline__ void stage_tile(unsigned int* lds, const unsigned int* gsrc, int tid) {
    const unsigned long long* s64 = (const unsigned long long*)gsrc;
    unsigned long long q[NJ];
#pragma unroll
    for (int j = 0; j < NJ; ++j) q[j] = ld_coh64(s64 + tid + 256 * j);
#pragma unroll
    for (int j = 0; j < NJ; ++j) {
        int f   = tid + 256 * j;
        int row = f / (RS / 2);
        int c   = (f % (RS / 2)) * 2;
        *(unsigned long long*)(lds + row * RS + (c ^ ((row & 7) << 2))) = q[j];
    }
}

// Unpack 8 packed hi/lo uints from swizzled LDS. i0 = row*RS + (start ^ sw)
// with start a multiple of 8; the second uint4 lives at i0 ^ 4 (swizzle flips
// only bits 2-4, so contiguity within each aligned 4-uint chunk is preserved).
__device__ __forceinline__ void unpack_lds(const unsigned int* lp, int i0, short8& ah, short8& al) {
    uint4 pa = *(const uint4*)(lp + i0);
    uint4 pb = *(const uint4*)(lp + (i0 ^ 4));
    unsigned int pv[8] = {pa.x, pa.y, pa.z, pa.w, pb.x, pb.y, pb.z, pb.w};
#pragma unroll
    for (int j = 0; j < 8; ++j) {
        ah[j] = (short)(pv[j] >> 16);
        al[j] = (short)(pv[j] & 0xffffu);
    }
}

__device__ __forceinline__ void cvt_x(const float* xp, short8& ah, short8& al) {
    float4 xa = *(const float4*)(xp);
    float4 xb = *(const float4*)(xp + 4);
    float xv[8] = {xa.x, xa.y, xa.z, xa.w, xb.x, xb.y, xb.z, xb.w};
#pragma unroll
    for (int j = 0; j < 8; ++j) {
        unsigned int u  = __float_as_uint(xv[j]);
        unsigned int hb = u & 0xffff0000u;
        float r = xv[j] - __uint_as_float(hb);
        ah[j] = (short)(u >> 16);
        al[j] = (short)(__float_as_uint(r) >> 16);
    }
}

// Sync primitives (r2-proven): release RMW arrival (orders the drained sc1 h
// stores before the counter bump; wbl2 ~free since L2 holds no dirty h);
// relaxed RMW spin (memory-side at the coherence point -- never stale, no
// per-poll cache maintenance). NO acquire fence anywhere: consumers get fresh
// h via the sc1 staging loads, so L1/L2 (weights, x, scratch) stay warm
// across all 512 steps.
__device__ __forceinline__ void arrive(unsigned int* cnt) {
    __hip_atomic_fetch_add(cnt, 1u, __ATOMIC_RELEASE, __HIP_MEMORY_SCOPE_AGENT);
}
__device__ __forceinline__ void spin_ge(unsigned int* cnt, unsigned int target) {
    while (__hip_atomic_fetch_add(cnt, 0u, __ATOMIC_RELAXED, __HIP_MEMORY_SCOPE_AGENT) < target) {}
}

// One LSTM layer role for one batch group (16 rows). Wave owns the group's
// m-tile x 2 column-tiles (8 units, all 4 gates). Weights pre-split to bf16
// hi/lo MFMA B-fragments in registers.
// MFMA 16x16x32_bf16: A: m=lane&15,k=quad*8+j ; D: col=lane&15, row=quad*4+r
//
// Split-counter dependency schedule (init arrivals = "step -1 done"):
//   L1@s : wait cntA>=8(s+1)  [peers' h1[s-1]]  and cntB>=4s    [h1-slot free:
//          L2 done s-2];  after storing h1[s]: cntA += 1  (=> cntA=8(s+2))
//   L2@s : wait cntA>=8(s+2)  [h1[s] ready]     and cntB>=4(s+1)[peers' h2[s-1]
//          + h2-slot free];  after storing h2[s]: cntB += 1  (=> cntB=4(s+2))
// L1 can run up to 2 steps ahead of L2; neither layer waits on the other's
// per-step stragglers (vs the old 12-arrival all-wait-all barrier).
template<int NKC, int KX, int GW, int UU, bool L1>
__device__ void lstm_role(const float* __restrict__ x,
                          const float* __restrict__ Wm, const float* __restrict__ Um,
                          const float* __restrict__ bias,
                          unsigned int* __restrict__ h1pk, unsigned int* __restrict__ h2pk,
                          float* __restrict__ out,
                          unsigned int* __restrict__ cntA, unsigned int* __restrict__ cntB,
                          int m0, int wid, float (*zex)[17],
                          unsigned int* __restrict__ ldsA, unsigned int* __restrict__ ldsB)
{
    const int tid  = threadIdx.x;
    const int lane = tid & 63;
    const int n    = lane & 15;
    const int quad = lane >> 4;
    const int gate = n >> 2;
    const int u0   = wid * 8;             // 8 units per wave (2 coltiles x 4)
    const int b_l  = lane >> 2;           // epilogue: batch-local 0..15
    const int ul   = lane & 3;            // epilogue: unit-local 0..3
    const int sw   = (n & 7) << 2;        // LDS read swizzle for this lane's row

    // ---- one-time: weight B-fragments (hi/lo split), bias ----
    short8 bh[2][NKC], bl[2][NKC];
    float bias_v[2];
#pragma unroll
    for (int c = 0; c < 2; ++c) {
        const int col = gate * UU + u0 + c * 4 + (n & 3);
        bias_v[c] = bias[col];
#pragma unroll
        for (int kc = 0; kc < NKC; ++kc) {
#pragma unroll
            for (int j = 0; j < 8; ++j) {
                int k = kc * 32 + quad * 8 + j;
                float w = (k < KX) ? Wm[k * GW + col] : Um[(k - KX) * GW + col];
                unsigned int p = split_pack(w);
                bh[c][kc][j] = (short)(p >> 16);
                bl[c][kc][j] = (short)(p & 0xffffu);
            }
        }
    }

    // ---- zero the "step -1" h slice this wave owns (ws is poisoned) ----
#pragma unroll
    for (int c = 0; c < 2; ++c) {
        if (L1) st_coh(&h1pk[32768 + (m0 + b_l) * 256 + u0 + c * 4 + ul], 0u);
        else    st_coh(&h2pk[16384 + (m0 + b_l) * 128 + u0 + c * 4 + ul], 0u);
    }
    float cst[2] = {0.f, 0.f};

    __syncthreads();                      // drains each wave's zero stores
    if (tid == 0) arrive(L1 ? cntA : cntB);

    for (int s = 0; s < 512; ++s) {
        // ---- wait for inputs (thread 0 spins, barrier publishes to block) ----
        if (tid == 0) {
            if (L1) { spin_ge(cntA, 8u * (s + 1)); if (s >= 2) spin_ge(cntB, 4u * (unsigned)s); }
            else    { spin_ge(cntA, 8u * (s + 2)); spin_ge(cntB, 4u * (s + 1)); }
        }
        __syncthreads();

        // ---- block-cooperative staging of h tiles into swizzled LDS ----
        if (L1) {
            stage_tile<256, 8>(ldsA, h1pk + ((s + 1) & 1) * 32768 + m0 * 256, tid);  // h1[s-1]
        } else {
            stage_tile<256, 8>(ldsA, h1pk + (s & 1) * 32768 + m0 * 256, tid);        // h1[s]
            stage_tile<128, 4>(ldsB, h2pk + ((s + 1) & 1) * 16384 + m0 * 128, tid);  // h2[s-1]
        }
        __syncthreads();

        // ---- compute step s ----
        floatx4 acc[2];
#pragma unroll
        for (int c = 0; c < 2; ++c)
            acc[c] = {bias_v[c], bias_v[c], bias_v[c], bias_v[c]};

        const float* xsrc = L1 ? (x + (size_t)(m0 + n) * (512 * 64) + s * 64) : nullptr;

#pragma unroll
        for (int kc = 0; kc < NKC; ++kc) {
            short8 ah, al;
            if (L1) {
                if (kc < 2) cvt_x(xsrc + kc * 32 + quad * 8, ah, al);
                else        unpack_lds(ldsA, n * 256 + (((kc - 2) * 32 + quad * 8) ^ sw), ah, al);
            } else {
                if (kc < 8) unpack_lds(ldsA, n * 256 + ((kc * 32 + quad * 8) ^ sw), ah, al);
                else        unpack_lds(ldsB, n * 128 + (((kc - 8) * 32 + quad * 8) ^ sw), ah, al);
            }
#pragma unroll
            for (int c = 0; c < 2; ++c) {
                acc[c] = __builtin_amdgcn_mfma_f32_16x16x32_bf16(ah, bh[c][kc], acc[c], 0, 0, 0);
                acc[c] = __builtin_amdgcn_mfma_f32_16x16x32_bf16(ah, bl[c][kc], acc[c], 0, 0, 0);
                acc[c] = __builtin_amdgcn_mfma_f32_16x16x32_bf16(al, bh[c][kc], acc[c], 0, 0, 0);
            }
        }

        // ---- epilogue: per coltile, gate-gather via per-wave LDS tile.
        // Wave-level lgkmcnt(0) drains the ds_writes of ALL lanes of this
        // wave before any lane's read; memory clobber stops reordering. ----
#pragma unroll
        for (int c = 0; c < 2; ++c) {
#pragma unroll
            for (int r = 0; r < 4; ++r) zex[quad * 4 + r][n] = acc[c][r];
            asm volatile("s_waitcnt lgkmcnt(0)" ::: "memory");
            float zi = zex[b_l][ 0 + ul];
            float zf = zex[b_l][ 4 + ul];
            float zg = zex[b_l][ 8 + ul];
            float zo = zex[b_l][12 + ul];
            asm volatile("s_waitcnt lgkmcnt(0)" ::: "memory");
            float ig = sigmoidf_(zi);
            float fg = sigmoidf_(zf);
            float gg = fmaxf(zg, 0.f);
            float og = sigmoidf_(zo);
            cst[c] = fg * cst[c] + ig * gg;
            float h = og * fmaxf(cst[c], 0.f);
            unsigned int p = split_pack(h);
            int b = m0 + b_l;
            if (L1) {
                st_coh(&h1pk[(s & 1) * 32768 + b * 256 + u0 + c * 4 + ul], p);
            } else {
                st_coh(&h2pk[(s & 1) * 16384 + b * 128 + u0 + c * 4 + ul], p);
                if (s == 511) out[b * 128 + u0 + c * 4 + ul] = h;
            }
        }

        // ---- publish: barrier drains all waves' sc1 stores (the compiler's
        // s_waitcnt vmcnt(0) before s_barrier), then one release arrival ----
        __syncthreads();
        if (tid == 0) arrive(L1 ? cntA : cntB);
    }
}

__global__ void __launch_bounds__(256, 1)
lstm_fused_kernel(const float* __restrict__ x,
                  const float* __restrict__ W1, const float* __restrict__ U1,
                  const float* __restrict__ b1,
                  const float* __restrict__ W2, const float* __restrict__ U2,
                  const float* __restrict__ b2,
                  float* __restrict__ out, unsigned int* __restrict__ ws)
{
    __shared__ float zex[4][16][17];         // per-wave gate-gather tiles
    __shared__ unsigned int ldsA[16 * 256];  // staged h1 tile (swizzled)
    __shared__ unsigned int ldsB[16 * 128];  // staged h2 tile (swizzled, L2 only)
    unsigned int* h1pk = ws;                 // [2][128][256] packed hi/lo bf16
    unsigned int* h2pk = ws + 65536;         // [2][128][128]
    const int g    = blockIdx.x & 7;         // batch group
    const int role = blockIdx.x >> 3;        // 0..7 layer1, 8..11 layer2
    const int wv   = threadIdx.x >> 6;
    const int m0   = g * 16;
    unsigned int* cntA = &g_cnt[g * 64];
    unsigned int* cntB = &g_cnt[g * 64 + 32];
    if (role < 8) {
        // layer1: 8 blocks x 4 waves = 32 unit-waves x 8 units = 256 units
        lstm_role<10, 64, 1024, 256, true >(x, W1, U1, b1, h1pk, h2pk, out,
                                            cntA, cntB, m0, role * 4 + wv, zex[wv], ldsA, ldsB);
    } else {
        // layer2: 4 blocks x 4 waves = 16 unit-waves x 8 units = 128 units
        lstm_role<12, 256, 512, 128, false>(x, W2, U2, b2, h1pk, h2pk, out,
                                            cntA, cntB, m0, (role - 8) * 4 + wv, zex[wv], ldsA, ldsB);
    }
}

// Pre-kernel (plain launch, cannot fail): zero barrier counters, write the
// diagnostic sentinel. Stream order publishes both to the main kernel.
// Signatures if main kernel fails: absmax~7 => main never ran (launch issue);
// absmax~0.162 => main ran but produced zeros (coherence issue).
__global__ void init_kernel(float* __restrict__ out) {
    int t = blockIdx.x * 256 + threadIdx.x;
    if (t < NG * 64) g_cnt[t] = 0u;
    if (t < 16384) out[t] = 7.0f;
}

extern "C" void kernel_launch(void* const* d_in, const int* in_sizes, int n_in,
                              void* d_out, int out_size, void* d_ws, size_t ws_size,
                              hipStream_t stream) {
    const float* x  = (const float*)d_in[0];
    const float* W1 = (const float*)d_in[1];
    const float* U1 = (const float*)d_in[2];
    const float* b1 = (const float*)d_in[3];
    const float* W2 = (const float*)d_in[4];
    const float* U2 = (const float*)d_in[5];
    const float* b2 = (const float*)d_in[6];
    float* out = (float*)d_out;
    unsigned int* ws = (unsigned int*)d_ws;
    init_kernel<<<64, 256, 0, stream>>>(out);
    lstm_fused_kernel<<<96, 256, 0, stream>>>(x, W1, U1, b1, W2, U2, b2, out, ws);
}